// Round 1
// baseline (3680.381 us; speedup 1.0000x reference)
//
#include <hip/hip_runtime.h>
#include <math.h>

// Problem constants (B=4, T=2048, C=1024, H=16, hs=64)
#define B_   4
#define T_   2048
#define C_   1024
#define H_   16
#define HS   64
#define HALF 32
#define QKV_N (3 * C_)      // 3072
#define M_    (B_ * T_)     // 8192

// ---------------------------------------------------------------------------
// GEMM: C = A @ B + bias.  A[M,K] row-major, B[K,N] row-major, bias[N].
// 64x64 block tile, BK=16, 256 threads, 4x4 micro-tile per thread. fp32.
// ---------------------------------------------------------------------------
template <int BM, int BN, int BK>
__global__ __launch_bounds__(256) void gemm_bias_kernel(
    const float* __restrict__ A, const float* __restrict__ Bm,
    const float* __restrict__ bias, float* __restrict__ Cm,
    int M, int N, int K)
{
    __shared__ float As[BK][BM + 1];   // stored transposed: As[k][row]
    __shared__ float Bs[BK][BN + 1];

    const int tid = threadIdx.x;       // 0..255
    const int tx  = tid % 16;
    const int ty  = tid / 16;
    const int row0 = blockIdx.y * BM;
    const int col0 = blockIdx.x * BN;

    float acc[4][4] = {};

    for (int k0 = 0; k0 < K; k0 += BK) {
        // A tile: BM x BK = 1024 floats; each thread one float4
        {
            int r = tid >> 2;              // 0..63
            int c = (tid & 3) * 4;         // 0,4,8,12
            const float4 v = *reinterpret_cast<const float4*>(
                &A[(size_t)(row0 + r) * K + k0 + c]);
            As[c + 0][r] = v.x; As[c + 1][r] = v.y;
            As[c + 2][r] = v.z; As[c + 3][r] = v.w;
        }
        // B tile: BK x BN = 1024 floats; each thread one float4
        {
            int r = tid >> 4;              // 0..15
            int c = (tid & 15) * 4;        // 0..60
            const float4 v = *reinterpret_cast<const float4*>(
                &Bm[(size_t)(k0 + r) * N + col0 + c]);
            Bs[r][c + 0] = v.x; Bs[r][c + 1] = v.y;
            Bs[r][c + 2] = v.z; Bs[r][c + 3] = v.w;
        }
        __syncthreads();

        #pragma unroll
        for (int k = 0; k < BK; ++k) {
            float a[4], b[4];
            #pragma unroll
            for (int i = 0; i < 4; ++i) a[i] = As[k][ty * 4 + i];
            #pragma unroll
            for (int j = 0; j < 4; ++j) b[j] = Bs[k][tx * 4 + j];
            #pragma unroll
            for (int i = 0; i < 4; ++i)
                #pragma unroll
                for (int j = 0; j < 4; ++j)
                    acc[i][j] += a[i] * b[j];
        }
        __syncthreads();
    }

    #pragma unroll
    for (int i = 0; i < 4; ++i) {
        const size_t r = row0 + ty * 4 + i;
        #pragma unroll
        for (int j = 0; j < 4; ++j) {
            const int c = col0 + tx * 4 + j;
            Cm[r * N + c] = acc[i][j] + bias[c];
        }
    }
}

// ---------------------------------------------------------------------------
// RoPE in place on the q and k slices of qkv[B,T,3C].
// Column layout: j = s*1024 + h*64 + d  (s=0:q, 1:k, 2:v)
// pair (2i, 2i+1): re = xe*cos - xo*sin ; ro = xe*sin + xo*cos
// ---------------------------------------------------------------------------
__global__ __launch_bounds__(256) void rope_kernel(float* __restrict__ qkv)
{
    const size_t total = (size_t)B_ * T_ * 2 * H_ * HALF;  // 8,388,608
    size_t idx = (size_t)blockIdx.x * blockDim.x + threadIdx.x;
    if (idx >= total) return;

    const int i = idx % HALF;
    const int h = (idx / HALF) % H_;
    const int s = (idx / (HALF * H_)) % 2;
    const int t = (idx / (HALF * H_ * 2)) % T_;
    const int b = idx / ((size_t)HALF * H_ * 2 * T_);

    const float theta = powf(10000.0f, -(float)i / (float)HALF);
    const float ang = (float)t * theta;
    float sn, cs;
    sincosf(ang, &sn, &cs);

    const size_t base = ((size_t)(b * T_ + t)) * QKV_N + s * C_ + h * HS + 2 * i;
    const float xe = qkv[base];
    const float xo = qkv[base + 1];
    qkv[base]     = xe * cs - xo * sn;
    qkv[base + 1] = xe * sn + xo * cs;
}

// ---------------------------------------------------------------------------
// Causal flash attention (fp32, vector ALU).
// Block: one (b, h, 16-query tile), 256 threads = 4 waves.
// Wave w owns q-rows {w*4 .. w*4+3}; lane = j (scores) or d (PV/output).
// K/V tiles of 64 staged in LDS (+1 pad: bank = (lane+d)%32, 2-way free).
// Output written as [B, T, H*hs] so the out-projection is a plain GEMM.
// ---------------------------------------------------------------------------
#define TQ 16
#define TK 64

__global__ __launch_bounds__(256) void attn_kernel(
    const float* __restrict__ qkv, float* __restrict__ out)
{
    const int blk = blockIdx.x;
    const int qt = blk % (T_ / TQ);
    const int h  = (blk / (T_ / TQ)) % H_;
    const int b  = blk / ((T_ / TQ) * H_);

    const int tid  = threadIdx.x;
    const int lane = tid & 63;
    const int w    = tid >> 6;

    __shared__ float Qs[TQ][HS];
    __shared__ float Ks[TK][HS + 1];
    __shared__ float Vs[TK][HS + 1];
    __shared__ float Ps[TQ][TK];

    // Load Q tile (16x64), already RoPE'd
    {
        int r = tid >> 4;              // 0..15
        int c = (tid & 15) * 4;
        const size_t g = ((size_t)(b * T_ + qt * TQ + r)) * QKV_N + h * HS + c;
        const float4 v = *reinterpret_cast<const float4*>(&qkv[g]);
        Qs[r][c + 0] = v.x; Qs[r][c + 1] = v.y;
        Qs[r][c + 2] = v.z; Qs[r][c + 3] = v.w;
    }

    float m[4], l[4], o[4];
    #pragma unroll
    for (int i = 0; i < 4; ++i) { m[i] = -INFINITY; l[i] = 0.f; o[i] = 0.f; }

    const int qg_max = qt * TQ + TQ - 1;
    const int nkt = qg_max / TK + 1;

    for (int kt = 0; kt < nkt; ++kt) {
        __syncthreads();   // previous iteration's PV done before overwrite
        // Load K and V tiles (64x64 each): thread -> row tid/4, 16 floats
        {
            const int r  = tid >> 2;
            const int c0 = (tid & 3) * 16;
            const size_t gk = ((size_t)(b * T_ + kt * TK + r)) * QKV_N + C_ + h * HS;
            const size_t gv = gk + C_;
            #pragma unroll
            for (int u = 0; u < 4; ++u) {
                const float4 kv = *reinterpret_cast<const float4*>(&qkv[gk + c0 + u * 4]);
                Ks[r][c0 + u * 4 + 0] = kv.x; Ks[r][c0 + u * 4 + 1] = kv.y;
                Ks[r][c0 + u * 4 + 2] = kv.z; Ks[r][c0 + u * 4 + 3] = kv.w;
                const float4 vv = *reinterpret_cast<const float4*>(&qkv[gv + c0 + u * 4]);
                Vs[r][c0 + u * 4 + 0] = vv.x; Vs[r][c0 + u * 4 + 1] = vv.y;
                Vs[r][c0 + u * 4 + 2] = vv.z; Vs[r][c0 + u * 4 + 3] = vv.w;
            }
        }
        __syncthreads();

        // Scores + online softmax. lane = j within tile.
        const int jg = kt * TK + lane;
        #pragma unroll
        for (int i = 0; i < 4; ++i) {
            const int qr = w * 4 + i;
            const int qg = qt * TQ + qr;
            float s;
            if (jg <= qg) {
                float acc = 0.f;
                #pragma unroll
                for (int d = 0; d < HS; ++d) acc += Qs[qr][d] * Ks[lane][d];
                s = acc * 0.125f;    // 1/sqrt(64)
            } else {
                s = -INFINITY;
            }
            float tm = s;
            #pragma unroll
            for (int off = 32; off > 0; off >>= 1)
                tm = fmaxf(tm, __shfl_xor(tm, off));
            const float nm = fmaxf(m[i], tm);         // finite: j=0 always valid
            const float p = expf(s - nm);             // masked lanes -> 0
            float sum = p;
            #pragma unroll
            for (int off = 32; off > 0; off >>= 1)
                sum += __shfl_xor(sum, off);
            const float scale = expf(m[i] - nm);
            l[i] = l[i] * scale + sum;
            o[i] *= scale;
            m[i] = nm;
            Ps[qr][lane] = p;
        }
        __syncthreads();

        // PV: lane = d. o[q][d] += sum_j P[q][j] * V[j][d]
        #pragma unroll
        for (int i = 0; i < 4; ++i) {
            const int qr = w * 4 + i;
            float acc = 0.f;
            #pragma unroll 8
            for (int j = 0; j < TK; ++j) acc += Ps[qr][j] * Vs[j][lane];
            o[i] += acc;
        }
    }

    // Write out[b, t, h*64 + d]
    #pragma unroll
    for (int i = 0; i < 4; ++i) {
        const int qg = qt * TQ + w * 4 + i;
        out[((size_t)(b * T_ + qg)) * C_ + h * HS + lane] = o[i] / l[i];
    }
}

// ---------------------------------------------------------------------------
extern "C" void kernel_launch(void* const* d_in, const int* in_sizes, int n_in,
                              void* d_out, int out_size, void* d_ws, size_t ws_size,
                              hipStream_t stream)
{
    const float* x    = (const float*)d_in[0];   // [B,T,C]
    const float* Wqkv = (const float*)d_in[1];   // [C,3C]
    const float* bqkv = (const float*)d_in[2];   // [3C]
    const float* Wout = (const float*)d_in[3];   // [C,C]
    const float* bout = (const float*)d_in[4];   // [C]
    float* out = (float*)d_out;                  // [B,T,C]

    // Workspace: qkv [B,T,3C] fp32 (100.66 MB) + attn_out [B,T,C] fp32 (33.55 MB)
    // = exactly 128 MiB.
    float* qkv  = (float*)d_ws;
    float* attn = qkv + (size_t)M_ * QKV_N;

    // 1) QKV projection: [8192,3072] = [8192,1024] @ [1024,3072] + bias
    gemm_bias_kernel<64, 64, 16><<<dim3(QKV_N / 64, M_ / 64), 256, 0, stream>>>(
        x, Wqkv, bqkv, qkv, M_, QKV_N, C_);

    // 2) RoPE in place on q,k slices
    {
        const size_t total = (size_t)B_ * T_ * 2 * H_ * HALF;
        rope_kernel<<<(total + 255) / 256, 256, 0, stream>>>(qkv);
    }

    // 3) Causal attention -> attn [B,T,C] (head-interleaved layout)
    attn_kernel<<<B_ * H_ * (T_ / TQ), 256, 0, stream>>>(qkv, attn);

    // 4) Output projection: [8192,1024] = [8192,1024] @ [1024,1024] + bias
    gemm_bias_kernel<64, 64, 16><<<dim3(C_ / 64, M_ / 64), 256, 0, stream>>>(
        attn, Wout, bout, out, M_, C_, C_);
}

// Round 2
// 389.924 us; speedup vs baseline: 9.4387x; 9.4387x over previous
//
#include <hip/hip_runtime.h>
#include <math.h>

// Problem constants (B=4, T=2048, C=1024, H=16, hs=64)
#define B_   4
#define T_   2048
#define C_   1024
#define H_   16
#define HS   64
#define HALF 32
#define QKV_N (3 * C_)      // 3072
#define M_    (B_ * T_)     // 8192

using bf16x8 = __attribute__((ext_vector_type(8))) short;
using f32x4  = __attribute__((ext_vector_type(4))) float;

__device__ __forceinline__ unsigned short f2bf(float f) {
    unsigned u = __builtin_bit_cast(unsigned, f);
    u = (u + 0x7FFFu + ((u >> 16) & 1u)) >> 16;
    return (unsigned short)u;
}
__device__ __forceinline__ float bf2f(unsigned short b) {
    return __builtin_bit_cast(float, (unsigned)b << 16);
}

__device__ __forceinline__ void gload16(const void* g, void* l) {
    __builtin_amdgcn_global_load_lds(
        (const __attribute__((address_space(1))) unsigned int*)g,
        (__attribute__((address_space(3))) unsigned int*)l, 16, 0, 0);
}

// ---------------------------------------------------------------------------
// fp32 -> bf16 cast, 8 elements/thread. n must be multiple of 8*blockDim.
// ---------------------------------------------------------------------------
__global__ __launch_bounds__(256) void cast_bf16_kernel(
    const float* __restrict__ in, unsigned short* __restrict__ out)
{
    const size_t i = ((size_t)blockIdx.x * 256 + threadIdx.x) * 8;
    const float4 a = *reinterpret_cast<const float4*>(&in[i]);
    const float4 b = *reinterpret_cast<const float4*>(&in[i + 4]);
    bf16x8 v;
    v[0] = f2bf(a.x); v[1] = f2bf(a.y); v[2] = f2bf(a.z); v[3] = f2bf(a.w);
    v[4] = f2bf(b.x); v[5] = f2bf(b.y); v[6] = f2bf(b.z); v[7] = f2bf(b.w);
    *reinterpret_cast<bf16x8*>(&out[i]) = v;
}

// ---------------------------------------------------------------------------
// Transpose + cast: W[K][N] fp32 -> Wt[N][K] bf16. 32x32 tiles.
// ---------------------------------------------------------------------------
__global__ __launch_bounds__(256) void transpose_cast_kernel(
    const float* __restrict__ W, unsigned short* __restrict__ Wt, int K, int N)
{
    __shared__ float tile[32][33];
    const int r = threadIdx.x / 32;      // 0..7
    const int c = threadIdx.x % 32;
    const int k0 = blockIdx.y * 32;
    const int n0 = blockIdx.x * 32;
    #pragma unroll
    for (int it = 0; it < 4; ++it)
        tile[r + it * 8][c] = W[(size_t)(k0 + r + it * 8) * N + n0 + c];
    __syncthreads();
    #pragma unroll
    for (int it = 0; it < 4; ++it)
        Wt[(size_t)(n0 + r + it * 8) * K + k0 + c] = f2bf(tile[c][r + it * 8]);
}

// ---------------------------------------------------------------------------
// RoPE sin/cos tables: tab[t*HALF + i], ang = t * 10000^(-i/HALF)
// ---------------------------------------------------------------------------
__global__ __launch_bounds__(256) void rope_table_kernel(
    float* __restrict__ tabs, float* __restrict__ tabc)
{
    const int idx = blockIdx.x * 256 + threadIdx.x;   // 0 .. T_*HALF-1
    const int t = idx / HALF;
    const int i = idx % HALF;
    const float theta = powf(10000.0f, -(float)i / (float)HALF);
    const float ang = (float)t * theta;
    float sn, cs;
    sincosf(ang, &sn, &cs);
    tabs[idx] = sn; tabc[idx] = cs;
}

// ---------------------------------------------------------------------------
// RoPE in place on bf16 qkv q,k slices. 4 pairs (8 bf16) per thread.
// chunk index: row = b*T+t ; c8 in [0,256): s = c8/128, within-slice col8 = c8%128
// ---------------------------------------------------------------------------
__global__ __launch_bounds__(256) void rope_bf16_kernel(
    unsigned short* __restrict__ qkv,
    const float* __restrict__ tabs, const float* __restrict__ tabc)
{
    const size_t idx = (size_t)blockIdx.x * 256 + threadIdx.x;  // 0 .. 8192*256-1
    const int row = idx >> 8;           // b*T + t
    const int c8  = idx & 255;
    const int s   = c8 >> 7;            // 0: q, 1: k
    const int cs64 = (c8 & 127) * 8;    // within-slice col (0..1016)
    const int d0   = cs64 & 63;         // within-head d
    const int t    = row & (T_ - 1);

    const size_t base = (size_t)row * QKV_N + s * C_ + (cs64 & ~63) + d0;
    bf16x8 v = *reinterpret_cast<const bf16x8*>(&qkv[base]);
    const float4 sn = *reinterpret_cast<const float4*>(&tabs[t * HALF + d0 / 2]);
    const float4 cs = *reinterpret_cast<const float4*>(&tabc[t * HALF + d0 / 2]);
    const float snv[4] = {sn.x, sn.y, sn.z, sn.w};
    const float csv[4] = {cs.x, cs.y, cs.z, cs.w};
    #pragma unroll
    for (int u = 0; u < 4; ++u) {
        const float xe = bf2f((unsigned short)v[2 * u]);
        const float xo = bf2f((unsigned short)v[2 * u + 1]);
        v[2 * u]     = f2bf(xe * csv[u] - xo * snv[u]);
        v[2 * u + 1] = f2bf(xe * snv[u] + xo * csv[u]);
    }
    *reinterpret_cast<bf16x8*>(&qkv[base]) = v;
}

// ---------------------------------------------------------------------------
// bf16 MFMA GEMM (m97 structure): C[M,N] = A[M,K] @ Bt[N,K]^T + bias
// 128x128 tile, BK=32, 256 threads = 4 waves (2x2), 64x64 per wave.
// global_load_lds width-16 staging, 2-barrier loop.
// BF16OUT: write bf16 (ushort) else fp32.
// ---------------------------------------------------------------------------
template <bool BF16OUT>
__global__ __launch_bounds__(256) void gemm_mfma_kernel(
    const unsigned short* __restrict__ A, const unsigned short* __restrict__ Bt,
    const float* __restrict__ bias, void* __restrict__ Cout,
    int M, int N, int K)
{
    __shared__ unsigned short As[128 * 32];
    __shared__ unsigned short Bs[128 * 32];

    const int tid  = threadIdx.x;
    const int lane = tid & 63;
    const int wave = tid >> 6;
    const int wr   = wave >> 1;
    const int wc   = wave & 1;
    const int row0 = blockIdx.y * 128;
    const int col0 = blockIdx.x * 128;

    const int l15 = lane & 15;
    const int l4  = lane >> 4;

    f32x4 acc[4][4] = {};

    // per-thread staging chunk: chunk e covers LDS elements [e*8, e*8+8)
    const int ar = tid >> 2, ac = (tid & 3) * 8;

    for (int k0 = 0; k0 < K; k0 += 32) {
        gload16(&A[(size_t)(row0 + ar) * K + k0 + ac],       &As[tid * 8]);
        gload16(&A[(size_t)(row0 + 64 + ar) * K + k0 + ac],  &As[(tid + 256) * 8]);
        gload16(&Bt[(size_t)(col0 + ar) * K + k0 + ac],      &Bs[tid * 8]);
        gload16(&Bt[(size_t)(col0 + 64 + ar) * K + k0 + ac], &Bs[(tid + 256) * 8]);
        __syncthreads();

        bf16x8 a[4], b[4];
        #pragma unroll
        for (int mi = 0; mi < 4; ++mi)
            a[mi] = *reinterpret_cast<const bf16x8*>(
                &As[(wr * 64 + mi * 16 + l15) * 32 + l4 * 8]);
        #pragma unroll
        for (int nj = 0; nj < 4; ++nj)
            b[nj] = *reinterpret_cast<const bf16x8*>(
                &Bs[(wc * 64 + nj * 16 + l15) * 32 + l4 * 8]);
        #pragma unroll
        for (int mi = 0; mi < 4; ++mi)
            #pragma unroll
            for (int nj = 0; nj < 4; ++nj)
                acc[mi][nj] = __builtin_amdgcn_mfma_f32_16x16x32_bf16(
                    a[mi], b[nj], acc[mi][nj], 0, 0, 0);
        __syncthreads();
    }

    float bv[4];
    #pragma unroll
    for (int nj = 0; nj < 4; ++nj)
        bv[nj] = bias[col0 + wc * 64 + nj * 16 + l15];

    #pragma unroll
    for (int mi = 0; mi < 4; ++mi) {
        #pragma unroll
        for (int r = 0; r < 4; ++r) {
            const size_t row = row0 + wr * 64 + mi * 16 + l4 * 4 + r;
            #pragma unroll
            for (int nj = 0; nj < 4; ++nj) {
                const int col = col0 + wc * 64 + nj * 16 + l15;
                const float v = acc[mi][nj][r] + bv[nj];
                if (BF16OUT)
                    ((unsigned short*)Cout)[row * N + col] = f2bf(v);
                else
                    ((float*)Cout)[row * N + col] = v;
            }
        }
    }
}

// ---------------------------------------------------------------------------
// MFMA flash attention (bf16 in/out, fp32 softmax state).
// Block: (b, h, 64 q-rows). 4 waves; wave w owns q-rows [w*16, w*16+16).
// K tiles of 64: Ks[64][72] (row j, col d), Vt[64][72] (row d, col j),
// Ps[64][72] (row q, col j). Pad 72 -> fragment reads conflict-free.
// ---------------------------------------------------------------------------
__global__ __launch_bounds__(256) void attn_mfma_kernel(
    const unsigned short* __restrict__ qkv, unsigned short* __restrict__ out)
{
    __shared__ unsigned short Ks[64 * 72];
    __shared__ unsigned short Vt[64 * 72];
    __shared__ unsigned short Ps[64 * 72];

    const int blk = blockIdx.x;
    const int qt = blk & 31;            // T_/64 = 32
    const int h  = (blk >> 5) & 15;
    const int b  = blk >> 9;

    const int tid  = threadIdx.x;
    const int lane = tid & 63;
    const int w    = tid >> 6;
    const int l15  = lane & 15;
    const int l4   = lane >> 4;

    const int q0 = qt * 64;

    // Q fragments (A-operand): row = q0 + w*16 + l15, k-chunk kk*32 + l4*8
    bf16x8 aq[2];
    {
        const size_t qrow = (size_t)(b * T_ + q0 + w * 16 + l15);
        const unsigned short* qp = &qkv[qrow * QKV_N + h * HS + l4 * 8];
        aq[0] = *reinterpret_cast<const bf16x8*>(qp);
        aq[1] = *reinterpret_cast<const bf16x8*>(qp + 32);
    }

    float m[4], l[4];
    f32x4 o[4] = {};
    #pragma unroll
    for (int r = 0; r < 4; ++r) { m[r] = -INFINITY; l[r] = 0.f; }

    // staging mapping: row sr = tid>>2, col group sc = (tid&3)*16
    const int sr = tid >> 2;
    const int sc = (tid & 3) * 16;

    const int nkt = qt + 1;
    for (int kt = 0; kt < nkt; ++kt) {
        __syncthreads();   // previous tile fully consumed
        {
            const size_t krow = (size_t)(b * T_ + kt * 64 + sr);
            const unsigned short* gk = &qkv[krow * QKV_N + C_ + h * HS + sc];
            const bf16x8 k1 = *reinterpret_cast<const bf16x8*>(gk);
            const bf16x8 k2 = *reinterpret_cast<const bf16x8*>(gk + 8);
            *reinterpret_cast<bf16x8*>(&Ks[sr * 72 + sc])     = k1;
            *reinterpret_cast<bf16x8*>(&Ks[sr * 72 + sc + 8]) = k2;
            const unsigned short* gv = gk + C_;
            const bf16x8 v1 = *reinterpret_cast<const bf16x8*>(gv);
            const bf16x8 v2 = *reinterpret_cast<const bf16x8*>(gv + 8);
            #pragma unroll
            for (int u = 0; u < 8; ++u) Vt[(sc + u) * 72 + sr] = (unsigned short)v1[u];
            #pragma unroll
            for (int u = 0; u < 8; ++u) Vt[(sc + 8 + u) * 72 + sr] = (unsigned short)v2[u];
        }
        __syncthreads();

        // S = Q @ K^T for this wave's 16 rows x 64 cols (4 col-tiles)
        f32x4 s[4];
        #pragma unroll
        for (int jt = 0; jt < 4; ++jt) {
            f32x4 z = {};
            #pragma unroll
            for (int kk = 0; kk < 2; ++kk) {
                const bf16x8 bk = *reinterpret_cast<const bf16x8*>(
                    &Ks[(jt * 16 + l15) * 72 + kk * 32 + l4 * 8]);
                z = __builtin_amdgcn_mfma_f32_16x16x32_bf16(aq[kk], bk, z, 0, 0, 0);
            }
            s[jt] = z;
        }

        // scale + causal mask; rows qg = q0 + w*16 + l4*4 + r, cols jg = kt*64 + jt*16 + l15
        const int qgb = q0 + w * 16 + l4 * 4;
        const int jgb = kt * 64 + l15;
        #pragma unroll
        for (int jt = 0; jt < 4; ++jt) {
            const int jg = jgb + jt * 16;
            #pragma unroll
            for (int r = 0; r < 4; ++r)
                s[jt][r] = (jg <= qgb + r) ? s[jt][r] * 0.125f : -INFINITY;
        }

        // online softmax (reduce across the 16 lanes of each row group)
        float tm[4], rs[4];
        #pragma unroll
        for (int r = 0; r < 4; ++r)
            tm[r] = fmaxf(fmaxf(s[0][r], s[1][r]), fmaxf(s[2][r], s[3][r]));
        #pragma unroll
        for (int off = 1; off < 16; off <<= 1)
            #pragma unroll
            for (int r = 0; r < 4; ++r)
                tm[r] = fmaxf(tm[r], __shfl_xor(tm[r], off));

        float nm[4], sf[4];
        #pragma unroll
        for (int r = 0; r < 4; ++r) {
            nm[r] = fmaxf(m[r], tm[r]);
            sf[r] = __expf(m[r] - nm[r]);
            rs[r] = 0.f;
        }
        #pragma unroll
        for (int jt = 0; jt < 4; ++jt) {
            #pragma unroll
            for (int r = 0; r < 4; ++r) {
                const float p = __expf(s[jt][r] - nm[r]);
                rs[r] += p;
                Ps[(w * 16 + l4 * 4 + r) * 72 + jt * 16 + l15] = f2bf(p);
            }
        }
        #pragma unroll
        for (int off = 1; off < 16; off <<= 1)
            #pragma unroll
            for (int r = 0; r < 4; ++r)
                rs[r] += __shfl_xor(rs[r], off);
        #pragma unroll
        for (int r = 0; r < 4; ++r) {
            l[r] = l[r] * sf[r] + rs[r];
            m[r] = nm[r];
        }
        #pragma unroll
        for (int dt = 0; dt < 4; ++dt)
            #pragma unroll
            for (int r = 0; r < 4; ++r)
                o[dt][r] *= sf[r];

        // PV: o[16 x 64] += P[16 x 64] @ V[64 x 64]
        #pragma unroll
        for (int kk = 0; kk < 2; ++kk) {
            const bf16x8 pa = *reinterpret_cast<const bf16x8*>(
                &Ps[(w * 16 + l15) * 72 + kk * 32 + l4 * 8]);
            #pragma unroll
            for (int dt = 0; dt < 4; ++dt) {
                const bf16x8 bv = *reinterpret_cast<const bf16x8*>(
                    &Vt[(dt * 16 + l15) * 72 + kk * 32 + l4 * 8]);
                o[dt] = __builtin_amdgcn_mfma_f32_16x16x32_bf16(pa, bv, o[dt], 0, 0, 0);
            }
        }
    }

    // write out[b, t, h*64 + d] (bf16)
    #pragma unroll
    for (int r = 0; r < 4; ++r) {
        const size_t row = (size_t)(b * T_ + q0 + w * 16 + l4 * 4 + r);
        const float inv = 1.0f / l[r];
        #pragma unroll
        for (int dt = 0; dt < 4; ++dt)
            out[row * C_ + h * HS + dt * 16 + l15] = f2bf(o[dt][r] * inv);
    }
}

// ---------------------------------------------------------------------------
extern "C" void kernel_launch(void* const* d_in, const int* in_sizes, int n_in,
                              void* d_out, int out_size, void* d_ws, size_t ws_size,
                              hipStream_t stream)
{
    const float* x    = (const float*)d_in[0];   // [B,T,C]
    const float* Wqkv = (const float*)d_in[1];   // [C,3C]
    const float* bqkv = (const float*)d_in[2];   // [3C]
    const float* Wout = (const float*)d_in[3];   // [C,C]
    const float* bout = (const float*)d_in[4];   // [C]
    float* out = (float*)d_out;                  // [B,T,C] fp32

    // Workspace layout (bf16 = ushort), all 16B-aligned:
    char* ws = (char*)d_ws;
    unsigned short* qkvb  = (unsigned short*)ws;                       // 50,331,648 B
    unsigned short* xb    = (unsigned short*)(ws + 50331648);          // 16,777,216 B
    unsigned short* attnb = (unsigned short*)(ws + 67108864);          // 16,777,216 B
    unsigned short* Wqkvt = (unsigned short*)(ws + 83886080);          //  6,291,456 B
    unsigned short* Woutt = (unsigned short*)(ws + 90177536);          //  2,097,152 B
    float* tabs           = (float*)(ws + 92274688);                   //    262,144 B
    float* tabc           = (float*)(ws + 92536832);                   //    262,144 B
    // total 92,798,976 B

    // 1) casts / transposes / tables
    cast_bf16_kernel<<<(size_t)M_ * C_ / (8 * 256), 256, 0, stream>>>(x, xb);
    transpose_cast_kernel<<<dim3(QKV_N / 32, C_ / 32), 256, 0, stream>>>(Wqkv, Wqkvt, C_, QKV_N);
    transpose_cast_kernel<<<dim3(C_ / 32, C_ / 32), 256, 0, stream>>>(Wout, Woutt, C_, C_);
    rope_table_kernel<<<(T_ * HALF) / 256, 256, 0, stream>>>(tabs, tabc);

    // 2) QKV projection (bf16 out)
    gemm_mfma_kernel<true><<<dim3(QKV_N / 128, M_ / 128), 256, 0, stream>>>(
        xb, Wqkvt, bqkv, qkvb, M_, QKV_N, C_);

    // 3) RoPE in place on q,k slices
    rope_bf16_kernel<<<(size_t)M_ * 256 / 256, 256, 0, stream>>>(qkvb, tabs, tabc);

    // 4) attention -> attnb [B,T,C] bf16
    attn_mfma_kernel<<<B_ * H_ * (T_ / 64), 256, 0, stream>>>(qkvb, attnb);

    // 5) output projection (fp32 out)
    gemm_mfma_kernel<false><<<dim3(C_ / 128, M_ / 128), 256, 0, stream>>>(
        attnb, Woutt, bout, out, M_, C_, C_);
}

// Round 3
// 290.821 us; speedup vs baseline: 12.6551x; 1.3408x over previous
//
#include <hip/hip_runtime.h>
#include <math.h>

// Problem constants (B=4, T=2048, C=1024, H=16, hs=64)
#define B_   4
#define T_   2048
#define C_   1024
#define H_   16
#define HS   64
#define HALF 32
#define QKV_N (3 * C_)      // 3072
#define M_    (B_ * T_)     // 8192

using bf16x8 = __attribute__((ext_vector_type(8))) short;
using f32x4  = __attribute__((ext_vector_type(4))) float;
using f32x16 = __attribute__((ext_vector_type(16))) float;

__device__ __forceinline__ unsigned short f2bf(float f) {
    unsigned u = __builtin_bit_cast(unsigned, f);
    u = (u + 0x7FFFu + ((u >> 16) & 1u)) >> 16;
    return (unsigned short)u;
}
__device__ __forceinline__ float bf2f(unsigned short b) {
    return __builtin_bit_cast(float, (unsigned)b << 16);
}
__device__ __forceinline__ unsigned cvtpk_bf16(float lo, float hi_) {
    unsigned r;
    asm("v_cvt_pk_bf16_f32 %0, %1, %2" : "=v"(r) : "v"(lo), "v"(hi_));
    return r;
}
__device__ __forceinline__ void gload16(const void* g, void* l) {
    __builtin_amdgcn_global_load_lds(
        (const __attribute__((address_space(1))) unsigned int*)g,
        (__attribute__((address_space(3))) unsigned int*)l, 16, 0, 0);
}

// ---------------------------------------------------------------------------
// fp32 -> bf16 cast, 8 elements/thread.
// ---------------------------------------------------------------------------
__global__ __launch_bounds__(256) void cast_bf16_kernel(
    const float* __restrict__ in, unsigned short* __restrict__ out)
{
    const size_t i = ((size_t)blockIdx.x * 256 + threadIdx.x) * 8;
    const float4 a = *reinterpret_cast<const float4*>(&in[i]);
    const float4 b = *reinterpret_cast<const float4*>(&in[i + 4]);
    bf16x8 v;
    v[0] = f2bf(a.x); v[1] = f2bf(a.y); v[2] = f2bf(a.z); v[3] = f2bf(a.w);
    v[4] = f2bf(b.x); v[5] = f2bf(b.y); v[6] = f2bf(b.z); v[7] = f2bf(b.w);
    *reinterpret_cast<bf16x8*>(&out[i]) = v;
}

// ---------------------------------------------------------------------------
// Transpose + cast: W[K][N] fp32 -> Wt[N][K] bf16. 32x32 tiles.
// ---------------------------------------------------------------------------
__global__ __launch_bounds__(256) void transpose_cast_kernel(
    const float* __restrict__ W, unsigned short* __restrict__ Wt, int K, int N)
{
    __shared__ float tile[32][33];
    const int r = threadIdx.x / 32;      // 0..7
    const int c = threadIdx.x % 32;
    const int k0 = blockIdx.y * 32;
    const int n0 = blockIdx.x * 32;
    #pragma unroll
    for (int it = 0; it < 4; ++it)
        tile[r + it * 8][c] = W[(size_t)(k0 + r + it * 8) * N + n0 + c];
    __syncthreads();
    #pragma unroll
    for (int it = 0; it < 4; ++it)
        Wt[(size_t)(n0 + r + it * 8) * K + k0 + c] = f2bf(tile[c][r + it * 8]);
}

// ---------------------------------------------------------------------------
// RoPE sin/cos tables
// ---------------------------------------------------------------------------
__global__ __launch_bounds__(256) void rope_table_kernel(
    float* __restrict__ tabs, float* __restrict__ tabc)
{
    const int idx = blockIdx.x * 256 + threadIdx.x;   // 0 .. T_*HALF-1
    const int t = idx / HALF;
    const int i = idx % HALF;
    const float theta = powf(10000.0f, -(float)i / (float)HALF);
    const float ang = (float)t * theta;
    float sn, cs;
    sincosf(ang, &sn, &cs);
    tabs[idx] = sn; tabc[idx] = cs;
}

// ---------------------------------------------------------------------------
// RoPE in place on bf16 qkv q,k slices. 4 pairs (8 bf16) per thread.
// ---------------------------------------------------------------------------
__global__ __launch_bounds__(256) void rope_bf16_kernel(
    unsigned short* __restrict__ qkv,
    const float* __restrict__ tabs, const float* __restrict__ tabc)
{
    const size_t idx = (size_t)blockIdx.x * 256 + threadIdx.x;
    const int row = idx >> 8;           // b*T + t
    const int c8  = idx & 255;
    const int s   = c8 >> 7;            // 0: q, 1: k
    const int cs64 = (c8 & 127) * 8;    // within-slice col (0..1016)
    const int d0   = cs64 & 63;         // within-head d
    const int t    = row & (T_ - 1);

    const size_t base = (size_t)row * QKV_N + s * C_ + (cs64 & ~63) + d0;
    bf16x8 v = *reinterpret_cast<const bf16x8*>(&qkv[base]);
    const float4 sn = *reinterpret_cast<const float4*>(&tabs[t * HALF + d0 / 2]);
    const float4 cs = *reinterpret_cast<const float4*>(&tabc[t * HALF + d0 / 2]);
    const float snv[4] = {sn.x, sn.y, sn.z, sn.w};
    const float csv[4] = {cs.x, cs.y, cs.z, cs.w};
    #pragma unroll
    for (int u = 0; u < 4; ++u) {
        const float xe = bf2f((unsigned short)v[2 * u]);
        const float xo = bf2f((unsigned short)v[2 * u + 1]);
        v[2 * u]     = f2bf(xe * csv[u] - xo * snv[u]);
        v[2 * u + 1] = f2bf(xe * snv[u] + xo * csv[u]);
    }
    *reinterpret_cast<bf16x8*>(&qkv[base]) = v;
}

// ---------------------------------------------------------------------------
// V^T precompute: qkv v-slice [b*T+t][2C + h*64 + d] -> vt[((b*H+h)*64+d)*T + t]
// 64x64 bf16 tiles per block.
// ---------------------------------------------------------------------------
__global__ __launch_bounds__(256) void vtrans_kernel(
    const unsigned short* __restrict__ qkv, unsigned short* __restrict__ vt)
{
    __shared__ unsigned short tile[64][72];
    const int tt = blockIdx.x & 31;
    const int h  = (blockIdx.x >> 5) & 15;
    const int b  = blockIdx.x >> 9;
    const int tid = threadIdx.x;
    const int r  = tid >> 2;          // 0..63
    const int c0 = (tid & 3) * 16;    // 0,16,32,48
    {
        const unsigned short* g =
            &qkv[(size_t)(b * T_ + tt * 64 + r) * QKV_N + 2 * C_ + h * HS + c0];
        const bf16x8 v0 = *reinterpret_cast<const bf16x8*>(g);
        const bf16x8 v1 = *reinterpret_cast<const bf16x8*>(g + 8);
        *reinterpret_cast<bf16x8*>(&tile[r][c0])     = v0;
        *reinterpret_cast<bf16x8*>(&tile[r][c0 + 8]) = v1;
    }
    __syncthreads();
    bf16x8 o0, o1;
    #pragma unroll
    for (int u = 0; u < 8; ++u) o0[u] = tile[c0 + u][r];
    #pragma unroll
    for (int u = 0; u < 8; ++u) o1[u] = tile[c0 + 8 + u][r];
    unsigned short* g = &vt[((size_t)((b * H_ + h) * HS + r)) * T_ + tt * 64 + c0];
    *reinterpret_cast<bf16x8*>(g)     = o0;
    *reinterpret_cast<bf16x8*>(g + 8) = o1;
}

// ---------------------------------------------------------------------------
// bf16 MFMA GEMM (m97 structure): C[M,N] = A[M,K] @ Bt[N,K]^T + bias
// ---------------------------------------------------------------------------
template <bool BF16OUT>
__global__ __launch_bounds__(256) void gemm_mfma_kernel(
    const unsigned short* __restrict__ A, const unsigned short* __restrict__ Bt,
    const float* __restrict__ bias, void* __restrict__ Cout,
    int M, int N, int K)
{
    __shared__ unsigned short As[128 * 32];
    __shared__ unsigned short Bs[128 * 32];

    const int tid  = threadIdx.x;
    const int lane = tid & 63;
    const int wave = tid >> 6;
    const int wr   = wave >> 1;
    const int wc   = wave & 1;
    const int row0 = blockIdx.y * 128;
    const int col0 = blockIdx.x * 128;

    const int l15 = lane & 15;
    const int l4  = lane >> 4;

    f32x4 acc[4][4] = {};
    const int ar = tid >> 2, ac = (tid & 3) * 8;

    for (int k0 = 0; k0 < K; k0 += 32) {
        gload16(&A[(size_t)(row0 + ar) * K + k0 + ac],       &As[tid * 8]);
        gload16(&A[(size_t)(row0 + 64 + ar) * K + k0 + ac],  &As[(tid + 256) * 8]);
        gload16(&Bt[(size_t)(col0 + ar) * K + k0 + ac],      &Bs[tid * 8]);
        gload16(&Bt[(size_t)(col0 + 64 + ar) * K + k0 + ac], &Bs[(tid + 256) * 8]);
        __syncthreads();

        bf16x8 a[4], b[4];
        #pragma unroll
        for (int mi = 0; mi < 4; ++mi)
            a[mi] = *reinterpret_cast<const bf16x8*>(
                &As[(wr * 64 + mi * 16 + l15) * 32 + l4 * 8]);
        #pragma unroll
        for (int nj = 0; nj < 4; ++nj)
            b[nj] = *reinterpret_cast<const bf16x8*>(
                &Bs[(wc * 64 + nj * 16 + l15) * 32 + l4 * 8]);
        #pragma unroll
        for (int mi = 0; mi < 4; ++mi)
            #pragma unroll
            for (int nj = 0; nj < 4; ++nj)
                acc[mi][nj] = __builtin_amdgcn_mfma_f32_16x16x32_bf16(
                    a[mi], b[nj], acc[mi][nj], 0, 0, 0);
        __syncthreads();
    }

    float bv[4];
    #pragma unroll
    for (int nj = 0; nj < 4; ++nj)
        bv[nj] = bias[col0 + wc * 64 + nj * 16 + l15];

    #pragma unroll
    for (int mi = 0; mi < 4; ++mi) {
        #pragma unroll
        for (int r = 0; r < 4; ++r) {
            const size_t row = row0 + wr * 64 + mi * 16 + l4 * 4 + r;
            #pragma unroll
            for (int nj = 0; nj < 4; ++nj) {
                const int col = col0 + wc * 64 + nj * 16 + l15;
                const float v = acc[mi][nj][r] + bv[nj];
                if (BF16OUT)
                    ((unsigned short*)Cout)[row * N + col] = f2bf(v);
                else
                    ((float*)Cout)[row * N + col] = v;
            }
        }
    }
}

// ---------------------------------------------------------------------------
// Flash attention, 32x32 MFMA, swapped-operand structure.
// Block: (b, h, 128 q-rows) = 4 waves x 32 q-rows. KVBLK = 64.
// S^T = mfma(K, Q): lane q = lane&31, j in regs -> in-register softmax.
// O^T = mfma(Vt, P): q stays lane&31 -> per-lane rescale/divide.
// K, Vt staged via global_load_lds with XOR-swizzled source (slot ^= row&7).
// ---------------------------------------------------------------------------
__global__ __launch_bounds__(256, 3) void attn_mfma2_kernel(
    const unsigned short* __restrict__ qkv,   // roped qkv, bf16
    const unsigned short* __restrict__ vt,    // V^T global [(b*H+h)*64+d][T]
    unsigned short* __restrict__ out)         // [B*T][C] bf16
{
    __shared__ unsigned short Ks[64 * 64];
    __shared__ unsigned short Vs[64 * 64];

    const int idx = blockIdx.x;
    const int qt = 15 - (idx & 15);          // heaviest tiles first
    const int h  = (idx >> 4) & 15;
    const int b  = idx >> 8;

    const int tid  = threadIdx.x;
    const int lane = tid & 63;
    const int w    = tid >> 6;
    const int l31  = lane & 31;
    const int hi   = lane >> 5;

    const int qw = qt * 128 + w * 32;        // wave's q base
    const int qg = qw + l31;                 // this lane's q (t index)

    // Q fragments: aq[kc] = Q[qg][kc*16 + hi*8 .. +8)
    bf16x8 aq[4];
    {
        const unsigned short* qp = &qkv[(size_t)(b * T_ + qg) * QKV_N + h * HS + hi * 8];
        #pragma unroll
        for (int kc = 0; kc < 4; ++kc)
            aq[kc] = *reinterpret_cast<const bf16x8*>(qp + kc * 16);
    }

    f32x16 acc0 = {}, acc1 = {};             // O^T accumulators (d-tiles 0,1)
    float mval = -INFINITY, lval = 0.f;

    const int sr = tid >> 3;                 // staging row (0..31) per half
    const int ss = tid & 7;                  // staging 16B slot
    const int nkt = qt * 2 + 2;
    const float SCALE = 0.18033688011112042f;  // 0.125 * log2(e)

    for (int kt = 0; kt < nkt; ++kt) {
        __syncthreads();
        #pragma unroll
        for (int n = 0; n < 2; ++n) {
            const int r  = n * 32 + sr;
            const int sk = (ss ^ (r & 7)) * 8;   // swizzled source slot (elems)
            gload16(&qkv[(size_t)(b * T_ + kt * 64 + r) * QKV_N + C_ + h * HS + sk],
                    &Ks[(n * 256 + tid) * 8]);
            gload16(&vt[((size_t)((b * H_ + h) * HS + r)) * T_ + kt * 64 + sk],
                    &Vs[(n * 256 + tid) * 8]);
        }
        __syncthreads();

        if (kt * 64 > qw + 31) continue;     // fully masked for this wave

        // ---- S^T = K @ Q^T  (two 32-j tiles) ----
        f32x16 st0 = {}, st1 = {};
        #pragma unroll
        for (int kc = 0; kc < 4; ++kc) {
            const int bo = kc * 32 + hi * 16;    // byte offset within 128B row
            const int r0 = l31;
            const bf16x8 ak0 = *reinterpret_cast<const bf16x8*>(
                &Ks[r0 * 64 + ((bo ^ ((r0 & 7) << 4)) >> 1)]);
            st0 = __builtin_amdgcn_mfma_f32_32x32x16_bf16(ak0, aq[kc], st0, 0, 0, 0);
            const int r1 = 32 + l31;
            const bf16x8 ak1 = *reinterpret_cast<const bf16x8*>(
                &Ks[r1 * 64 + ((bo ^ ((r1 & 7) << 4)) >> 1)]);
            st1 = __builtin_amdgcn_mfma_f32_32x32x16_bf16(ak1, aq[kc], st1, 0, 0, 0);
        }

        // ---- scale + causal mask (exp2 space) ----
        float p[32];
        if (kt * 64 + 63 > qw) {
            #pragma unroll
            for (int r = 0; r < 16; ++r) {
                const int j0 = kt * 64 + (r & 3) + 8 * (r >> 2) + 4 * hi;
                p[r]      = (j0      <= qg) ? st0[r] * SCALE : -INFINITY;
                p[r + 16] = (j0 + 32 <= qg) ? st1[r] * SCALE : -INFINITY;
            }
        } else {
            #pragma unroll
            for (int r = 0; r < 16; ++r) {
                p[r]      = st0[r] * SCALE;
                p[r + 16] = st1[r] * SCALE;
            }
        }

        // ---- online softmax, per-lane (q = lane&31) ----
        float tm = p[0];
        #pragma unroll
        for (int r = 1; r < 32; ++r) tm = fmaxf(tm, p[r]);
        tm = fmaxf(tm, __shfl_xor(tm, 32));

        const bool upd = (tm > mval + 8.f);          // defer-max THR=8 (log2)
        if (__ballot(upd)) {
            const float nm = upd ? tm : mval;
            const float sf = exp2f(mval - nm);
            lval *= sf;
            #pragma unroll
            for (int r = 0; r < 16; ++r) { acc0[r] *= sf; acc1[r] *= sf; }
            mval = nm;
        }

        float rs = 0.f;
        #pragma unroll
        for (int r = 0; r < 32; ++r) { p[r] = exp2f(p[r] - mval); rs += p[r]; }
        rs += __shfl_xor(rs, 32);
        lval += rs;

        // ---- P fragments (cvt_pk + shfl_xor 32) and PV: O^T += Vt @ P ----
        #pragma unroll
        for (int jt = 0; jt < 2; ++jt) {
            #pragma unroll
            for (int c = 0; c < 2; ++c) {
                const int base = jt * 16 + c * 8;
                const unsigned pa = cvtpk_bf16(p[base + 0], p[base + 1]);
                const unsigned pb = cvtpk_bf16(p[base + 2], p[base + 3]);
                const unsigned pc = cvtpk_bf16(p[base + 4], p[base + 5]);
                const unsigned pd = cvtpk_bf16(p[base + 6], p[base + 7]);
                const unsigned pas = (unsigned)__shfl_xor((int)pa, 32);
                const unsigned pbs = (unsigned)__shfl_xor((int)pb, 32);
                const unsigned pcs = (unsigned)__shfl_xor((int)pc, 32);
                const unsigned pds = (unsigned)__shfl_xor((int)pd, 32);
                int4 bw;
                bw.x = (int)(hi ? pcs : pa);
                bw.y = (int)(hi ? pds : pb);
                bw.z = (int)(hi ? pc  : pas);
                bw.w = (int)(hi ? pd  : pbs);
                const bf16x8 bfrag = __builtin_bit_cast(bf16x8, bw);

                const int jb = (jt * 2 + c) * 32 + hi * 16;  // byte offset in Vs row
                const int r0 = l31;
                const bf16x8 av0 = *reinterpret_cast<const bf16x8*>(
                    &Vs[r0 * 64 + ((jb ^ ((r0 & 7) << 4)) >> 1)]);
                acc0 = __builtin_amdgcn_mfma_f32_32x32x16_bf16(av0, bfrag, acc0, 0, 0, 0);
                const int r1 = 32 + l31;
                const bf16x8 av1 = *reinterpret_cast<const bf16x8*>(
                    &Vs[r1 * 64 + ((jb ^ ((r1 & 7) << 4)) >> 1)]);
                acc1 = __builtin_amdgcn_mfma_f32_32x32x16_bf16(av1, bfrag, acc1, 0, 0, 0);
            }
        }
    }

    // ---- write O = acc^T / l : lane q = lane&31, d = dt*32 + 8g + 4hi + 0..3
    const float inv = 1.0f / lval;
    unsigned short* orow = &out[(size_t)(b * T_ + qg) * C_ + h * HS];
    #pragma unroll
    for (int g = 0; g < 4; ++g) {
        uint2 wv;
        wv.x = cvtpk_bf16(acc0[4 * g + 0] * inv, acc0[4 * g + 1] * inv);
        wv.y = cvtpk_bf16(acc0[4 * g + 2] * inv, acc0[4 * g + 3] * inv);
        *reinterpret_cast<uint2*>(&orow[8 * g + 4 * hi]) = wv;
        uint2 wv1;
        wv1.x = cvtpk_bf16(acc1[4 * g + 0] * inv, acc1[4 * g + 1] * inv);
        wv1.y = cvtpk_bf16(acc1[4 * g + 2] * inv, acc1[4 * g + 3] * inv);
        *reinterpret_cast<uint2*>(&orow[32 + 8 * g + 4 * hi]) = wv1;
    }
}

// ---------------------------------------------------------------------------
extern "C" void kernel_launch(void* const* d_in, const int* in_sizes, int n_in,
                              void* d_out, int out_size, void* d_ws, size_t ws_size,
                              hipStream_t stream)
{
    const float* x    = (const float*)d_in[0];   // [B,T,C]
    const float* Wqkv = (const float*)d_in[1];   // [C,3C]
    const float* bqkv = (const float*)d_in[2];   // [3C]
    const float* Wout = (const float*)d_in[3];   // [C,C]
    const float* bout = (const float*)d_in[4];   // [C]
    float* out = (float*)d_out;                  // [B,T,C] fp32

    char* ws = (char*)d_ws;
    unsigned short* qkvb  = (unsigned short*)ws;                       // 50,331,648
    unsigned short* xb    = (unsigned short*)(ws + 50331648);          // 16,777,216
    unsigned short* attnb = (unsigned short*)(ws + 67108864);          // 16,777,216
    unsigned short* vt_g  = (unsigned short*)(ws + 83886080);          // 16,777,216
    unsigned short* Wqkvt = (unsigned short*)(ws + 100663296);         //  6,291,456
    unsigned short* Woutt = (unsigned short*)(ws + 106954752);         //  2,097,152
    float* tabs           = (float*)(ws + 109051904);                  //    262,144
    float* tabc           = (float*)(ws + 109314048);                  //    262,144

    // 1) casts / transposes / tables
    cast_bf16_kernel<<<(size_t)M_ * C_ / (8 * 256), 256, 0, stream>>>(x, xb);
    transpose_cast_kernel<<<dim3(QKV_N / 32, C_ / 32), 256, 0, stream>>>(Wqkv, Wqkvt, C_, QKV_N);
    transpose_cast_kernel<<<dim3(C_ / 32, C_ / 32), 256, 0, stream>>>(Wout, Woutt, C_, C_);
    rope_table_kernel<<<(T_ * HALF) / 256, 256, 0, stream>>>(tabs, tabc);

    // 2) QKV projection (bf16 out)
    gemm_mfma_kernel<true><<<dim3(QKV_N / 128, M_ / 128), 256, 0, stream>>>(
        xb, Wqkvt, bqkv, qkvb, M_, QKV_N, C_);

    // 3) V^T precompute + RoPE on q,k slices
    vtrans_kernel<<<B_ * H_ * (T_ / 64), 256, 0, stream>>>(qkvb, vt_g);
    rope_bf16_kernel<<<(size_t)M_ * 256 / 256, 256, 0, stream>>>(qkvb, tabs, tabc);

    // 4) attention -> attnb [B,T,C] bf16
    attn_mfma2_kernel<<<B_ * H_ * (T_ / 128), 256, 0, stream>>>(qkvb, vt_g, attnb);

    // 5) output projection (fp32 out)
    gemm_mfma_kernel<false><<<dim3(C_ / 128, M_ / 128), 256, 0, stream>>>(
        attnb, Woutt, bout, out, M_, C_, C_);
}

// Round 4
// 225.941 us; speedup vs baseline: 16.2892x; 1.2872x over previous
//
#include <hip/hip_runtime.h>
#include <math.h>

// Problem constants (B=4, T=2048, C=1024, H=16, hs=64)
#define B_   4
#define T_   2048
#define C_   1024
#define H_   16
#define HS   64
#define HALF 32
#define QKV_N (3 * C_)      // 3072
#define M_    (B_ * T_)     // 8192

using bf16x8 = __attribute__((ext_vector_type(8))) short;
using f32x4  = __attribute__((ext_vector_type(4))) float;
using f32x16 = __attribute__((ext_vector_type(16))) float;

__device__ __forceinline__ unsigned short f2bf(float f) {
    unsigned u = __builtin_bit_cast(unsigned, f);
    u = (u + 0x7FFFu + ((u >> 16) & 1u)) >> 16;
    return (unsigned short)u;
}
__device__ __forceinline__ float bf2f(unsigned short b) {
    return __builtin_bit_cast(float, (unsigned)b << 16);
}
__device__ __forceinline__ unsigned cvtpk_bf16(float lo, float hi_) {
    unsigned r;
    asm("v_cvt_pk_bf16_f32 %0, %1, %2" : "=v"(r) : "v"(lo), "v"(hi_));
    return r;
}
__device__ __forceinline__ void gload16(const void* g, void* l) {
    __builtin_amdgcn_global_load_lds(
        (const __attribute__((address_space(1))) unsigned int*)g,
        (__attribute__((address_space(3))) unsigned int*)l, 16, 0, 0);
}

// ---------------------------------------------------------------------------
// fp32 -> bf16 cast, 8 elements/thread.
// ---------------------------------------------------------------------------
__global__ __launch_bounds__(256) void cast_bf16_kernel(
    const float* __restrict__ in, unsigned short* __restrict__ out)
{
    const size_t i = ((size_t)blockIdx.x * 256 + threadIdx.x) * 8;
    const float4 a = *reinterpret_cast<const float4*>(&in[i]);
    const float4 b = *reinterpret_cast<const float4*>(&in[i + 4]);
    bf16x8 v;
    v[0] = f2bf(a.x); v[1] = f2bf(a.y); v[2] = f2bf(a.z); v[3] = f2bf(a.w);
    v[4] = f2bf(b.x); v[5] = f2bf(b.y); v[6] = f2bf(b.z); v[7] = f2bf(b.w);
    *reinterpret_cast<bf16x8*>(&out[i]) = v;
}

// ---------------------------------------------------------------------------
// Transpose + cast: W[K][N] fp32 -> Wt[N][K] bf16. 32x32 tiles.
// ---------------------------------------------------------------------------
__global__ __launch_bounds__(256) void transpose_cast_kernel(
    const float* __restrict__ W, unsigned short* __restrict__ Wt, int K, int N)
{
    __shared__ float tile[32][33];
    const int r = threadIdx.x / 32;      // 0..7
    const int c = threadIdx.x % 32;
    const int k0 = blockIdx.y * 32;
    const int n0 = blockIdx.x * 32;
    #pragma unroll
    for (int it = 0; it < 4; ++it)
        tile[r + it * 8][c] = W[(size_t)(k0 + r + it * 8) * N + n0 + c];
    __syncthreads();
    #pragma unroll
    for (int it = 0; it < 4; ++it)
        Wt[(size_t)(n0 + r + it * 8) * K + k0 + c] = f2bf(tile[c][r + it * 8]);
}

// ---------------------------------------------------------------------------
// RoPE table: tab[t*HALF + i] = (sin, cos) of t * 10000^(-i/HALF)
// ---------------------------------------------------------------------------
__global__ __launch_bounds__(256) void rope_table_kernel(float2* __restrict__ tab)
{
    const int idx = blockIdx.x * 256 + threadIdx.x;   // 0 .. T_*HALF-1
    const int t = idx / HALF;
    const int i = idx % HALF;
    const float theta = powf(10000.0f, -(float)i / (float)HALF);
    const float ang = (float)t * theta;
    float sn, cs;
    sincosf(ang, &sn, &cs);
    tab[idx] = make_float2(sn, cs);
}

// ---------------------------------------------------------------------------
// V^T precompute: qkv v-slice [b*T+t][2C + h*64 + d] -> vt[((b*H+h)*64+d)*T + t]
// ---------------------------------------------------------------------------
__global__ __launch_bounds__(256) void vtrans_kernel(
    const unsigned short* __restrict__ qkv, unsigned short* __restrict__ vt)
{
    __shared__ unsigned short tile[64][72];
    const int tt = blockIdx.x & 31;
    const int h  = (blockIdx.x >> 5) & 15;
    const int b  = blockIdx.x >> 9;
    const int tid = threadIdx.x;
    const int r  = tid >> 2;          // 0..63
    const int c0 = (tid & 3) * 16;    // 0,16,32,48
    {
        const unsigned short* g =
            &qkv[(size_t)(b * T_ + tt * 64 + r) * QKV_N + 2 * C_ + h * HS + c0];
        const bf16x8 v0 = *reinterpret_cast<const bf16x8*>(g);
        const bf16x8 v1 = *reinterpret_cast<const bf16x8*>(g + 8);
        *reinterpret_cast<bf16x8*>(&tile[r][c0])     = v0;
        *reinterpret_cast<bf16x8*>(&tile[r][c0 + 8]) = v1;
    }
    __syncthreads();
    bf16x8 o0, o1;
    #pragma unroll
    for (int u = 0; u < 8; ++u) o0[u] = tile[c0 + u][r];
    #pragma unroll
    for (int u = 0; u < 8; ++u) o1[u] = tile[c0 + 8 + u][r];
    unsigned short* g = &vt[((size_t)((b * H_ + h) * HS + r)) * T_ + tt * 64 + c0];
    *reinterpret_cast<bf16x8*>(g)     = o0;
    *reinterpret_cast<bf16x8*>(g + 8) = o1;
}

// ---------------------------------------------------------------------------
// bf16 MFMA GEMM: C[M,N] = A[M,K] @ Bt[N,K]^T + bias, optional fused RoPE
// on columns < 2048 (q,k slices). 128x128 tile, BK=32, 4 waves.
// ---------------------------------------------------------------------------
template <bool BF16OUT, bool ROPE>
__global__ __launch_bounds__(256) void gemm_mfma_kernel(
    const unsigned short* __restrict__ A, const unsigned short* __restrict__ Bt,
    const float* __restrict__ bias, const float2* __restrict__ tab,
    void* __restrict__ Cout, int M, int N, int K)
{
    __shared__ unsigned short As[128 * 32];
    __shared__ unsigned short Bs[128 * 32];

    const int tid  = threadIdx.x;
    const int lane = tid & 63;
    const int wave = tid >> 6;
    const int wr   = wave >> 1;
    const int wc   = wave & 1;
    const int row0 = blockIdx.y * 128;
    const int col0 = blockIdx.x * 128;

    const int l15 = lane & 15;
    const int l4  = lane >> 4;

    f32x4 acc[4][4] = {};
    const int ar = tid >> 2, ac = (tid & 3) * 8;

    for (int k0 = 0; k0 < K; k0 += 32) {
        gload16(&A[(size_t)(row0 + ar) * K + k0 + ac],       &As[tid * 8]);
        gload16(&A[(size_t)(row0 + 64 + ar) * K + k0 + ac],  &As[(tid + 256) * 8]);
        gload16(&Bt[(size_t)(col0 + ar) * K + k0 + ac],      &Bs[tid * 8]);
        gload16(&Bt[(size_t)(col0 + 64 + ar) * K + k0 + ac], &Bs[(tid + 256) * 8]);
        __syncthreads();

        bf16x8 a[4], b[4];
        #pragma unroll
        for (int mi = 0; mi < 4; ++mi)
            a[mi] = *reinterpret_cast<const bf16x8*>(
                &As[(wr * 64 + mi * 16 + l15) * 32 + l4 * 8]);
        #pragma unroll
        for (int nj = 0; nj < 4; ++nj)
            b[nj] = *reinterpret_cast<const bf16x8*>(
                &Bs[(wc * 64 + nj * 16 + l15) * 32 + l4 * 8]);
        #pragma unroll
        for (int mi = 0; mi < 4; ++mi)
            #pragma unroll
            for (int nj = 0; nj < 4; ++nj)
                acc[mi][nj] = __builtin_amdgcn_mfma_f32_16x16x32_bf16(
                    a[mi], b[nj], acc[mi][nj], 0, 0, 0);
        __syncthreads();
    }

    float bv[4];
    #pragma unroll
    for (int nj = 0; nj < 4; ++nj)
        bv[nj] = bias[col0 + wc * 64 + nj * 16 + l15];

    const bool doRope = ROPE && (col0 < 2 * C_);   // block-uniform

    #pragma unroll
    for (int mi = 0; mi < 4; ++mi) {
        #pragma unroll
        for (int r = 0; r < 4; ++r) {
            const int row = row0 + wr * 64 + mi * 16 + l4 * 4 + r;
            const int t   = row & (T_ - 1);
            #pragma unroll
            for (int nj = 0; nj < 4; ++nj) {
                const int col = col0 + wc * 64 + nj * 16 + l15;
                float v = acc[mi][nj][r] + bv[nj];
                if (doRope) {
                    const float partner = __shfl_xor(v, 1);
                    const float2 sc = tab[t * HALF + ((col & 63) >> 1)];
                    // even d: xe*cos - xo*sin ; odd d: xe*sin + xo*cos
                    v = v * sc.y + ((col & 1) ? partner : -partner) * sc.x;
                }
                if (BF16OUT)
                    ((unsigned short*)Cout)[(size_t)row * N + col] = f2bf(v);
                else
                    ((float*)Cout)[(size_t)row * N + col] = v;
            }
        }
    }
}

// ---------------------------------------------------------------------------
// Flash attention, 32x32 MFMA, swapped operands, PAIRED causal q-tiles.
// Block: (b, h, qp) handles q-tiles qtA=qp and qtB=15-qp (128 rows each)
// -> every block processes exactly ~34 k-subtiles (balanced).
// K/V staged once per 128-k chunk, shared by both q-tiles.
// Block index: idx = qp*64 + bh so all 8 blocks of one (b,h) share an XCD.
// ---------------------------------------------------------------------------
__global__ __launch_bounds__(256, 2) void attn_mfma3_kernel(
    const unsigned short* __restrict__ qkv,   // roped qkv, bf16
    const unsigned short* __restrict__ vt,    // V^T global [(b*H+h)*64+d][T]
    unsigned short* __restrict__ out)         // [B*T][C] bf16
{
    __shared__ unsigned short Ks[128 * 64];   // [j 0..127][d 0..63], swizzled
    __shared__ unsigned short Vs[64 * 128];   // [d 0..63][j 0..127], swizzled

    const int idx = blockIdx.x;
    const int bh  = idx & 63;                 // b*16 + h
    const int qp  = idx >> 6;                 // 0..7
    const int b   = bh >> 4;
    const int h   = bh & 15;
    const int qtA = qp;
    const int qtB = 15 - qp;

    const int tid  = threadIdx.x;
    const int lane = tid & 63;
    const int w    = tid >> 6;
    const int l31  = lane & 31;
    const int hi   = lane >> 5;

    const int qwA = qtA * 128 + w * 32;
    const int qgA = qwA + l31;
    const int qwB = qtB * 128 + w * 32;
    const int qgB = qwB + l31;

    // Q fragments
    bf16x8 aqA[4], aqB[4];
    {
        const unsigned short* qpA = &qkv[(size_t)(b * T_ + qgA) * QKV_N + h * HS + hi * 8];
        const unsigned short* qpB = &qkv[(size_t)(b * T_ + qgB) * QKV_N + h * HS + hi * 8];
        #pragma unroll
        for (int kc = 0; kc < 4; ++kc) {
            aqA[kc] = *reinterpret_cast<const bf16x8*>(qpA + kc * 16);
            aqB[kc] = *reinterpret_cast<const bf16x8*>(qpB + kc * 16);
        }
    }

    f32x16 accA0 = {}, accA1 = {}, accB0 = {}, accB1 = {};
    float mA = -INFINITY, lA = 0.f, mB = -INFINITY, lB = 0.f;

    const float SCALE = 0.18033688011112042f;  // 0.125 * log2(e)

    auto process = [&](const bf16x8* aq, f32x16& a0, f32x16& a1,
                       float& mval, float& lval, int qw, int qg,
                       int sub, int kbase) {
        // ---- S^T = K @ Q^T (two 32-j tiles within this 64 half) ----
        f32x16 st0 = {}, st1 = {};
        #pragma unroll
        for (int kc = 0; kc < 4; ++kc) {
            const int bo = kc * 32 + hi * 16;          // byte offset in 128B K row
            const int r0 = sub * 64 + l31;
            const bf16x8 ak0 = *reinterpret_cast<const bf16x8*>(
                &Ks[r0 * 64 + ((bo ^ ((r0 & 7) << 4)) >> 1)]);
            st0 = __builtin_amdgcn_mfma_f32_32x32x16_bf16(ak0, aq[kc], st0, 0, 0, 0);
            const int r1 = r0 + 32;
            const bf16x8 ak1 = *reinterpret_cast<const bf16x8*>(
                &Ks[r1 * 64 + ((bo ^ ((r1 & 7) << 4)) >> 1)]);
            st1 = __builtin_amdgcn_mfma_f32_32x32x16_bf16(ak1, aq[kc], st1, 0, 0, 0);
        }

        // ---- scale + causal mask (exp2 space) ----
        float p[32];
        if (kbase + 63 > qw) {
            #pragma unroll
            for (int r = 0; r < 16; ++r) {
                const int j0 = kbase + (r & 3) + 8 * (r >> 2) + 4 * hi;
                p[r]      = (j0      <= qg) ? st0[r] * SCALE : -INFINITY;
                p[r + 16] = (j0 + 32 <= qg) ? st1[r] * SCALE : -INFINITY;
            }
        } else {
            #pragma unroll
            for (int r = 0; r < 16; ++r) {
                p[r]      = st0[r] * SCALE;
                p[r + 16] = st1[r] * SCALE;
            }
        }

        // ---- online softmax, per-lane (q = lane&31) ----
        float tm = p[0];
        #pragma unroll
        for (int r = 1; r < 32; ++r) tm = fmaxf(tm, p[r]);
        tm = fmaxf(tm, __shfl_xor(tm, 32));

        const bool upd = (tm > mval + 8.f);          // defer-max THR=8 (log2)
        if (__ballot(upd)) {
            const float nm = upd ? tm : mval;
            const float sf = exp2f(mval - nm);
            lval *= sf;
            #pragma unroll
            for (int r = 0; r < 16; ++r) { a0[r] *= sf; a1[r] *= sf; }
            mval = nm;
        }

        float rs = 0.f;
        #pragma unroll
        for (int r = 0; r < 32; ++r) { p[r] = exp2f(p[r] - mval); rs += p[r]; }
        rs += __shfl_xor(rs, 32);
        lval += rs;

        // ---- P fragments + PV: O^T += Vt @ P ----
        #pragma unroll
        for (int jt = 0; jt < 2; ++jt) {
            #pragma unroll
            for (int c = 0; c < 2; ++c) {
                const int base = jt * 16 + c * 8;
                const unsigned pa = cvtpk_bf16(p[base + 0], p[base + 1]);
                const unsigned pb = cvtpk_bf16(p[base + 2], p[base + 3]);
                const unsigned pc = cvtpk_bf16(p[base + 4], p[base + 5]);
                const unsigned pd = cvtpk_bf16(p[base + 6], p[base + 7]);
                const unsigned pas = (unsigned)__shfl_xor((int)pa, 32);
                const unsigned pbs = (unsigned)__shfl_xor((int)pb, 32);
                const unsigned pcs = (unsigned)__shfl_xor((int)pc, 32);
                const unsigned pds = (unsigned)__shfl_xor((int)pd, 32);
                int4 bw;
                bw.x = (int)(hi ? pcs : pa);
                bw.y = (int)(hi ? pds : pb);
                bw.z = (int)(hi ? pc  : pas);
                bw.w = (int)(hi ? pd  : pbs);
                const bf16x8 bfrag = __builtin_bit_cast(bf16x8, bw);

                const int lslot = sub * 8 + (jt * 2 + c) * 2 + hi;  // 16B slot in 256B Vs row
                const int d0 = l31;
                const bf16x8 av0 = *reinterpret_cast<const bf16x8*>(
                    &Vs[d0 * 128 + (lslot ^ (d0 & 7)) * 8]);
                a0 = __builtin_amdgcn_mfma_f32_32x32x16_bf16(av0, bfrag, a0, 0, 0, 0);
                const int d1 = 32 + l31;
                const bf16x8 av1 = *reinterpret_cast<const bf16x8*>(
                    &Vs[d1 * 128 + (lslot ^ (d1 & 7)) * 8]);
                a1 = __builtin_amdgcn_mfma_f32_32x32x16_bf16(av1, bfrag, a1, 0, 0, 0);
            }
        }
    };

    const int nIter = qtB + 1;                       // 128-wide k chunks
    for (int it = 0; it < nIter; ++it) {
        __syncthreads();
        // ---- stage K (128 x 64) and Vt (64 x 128), XOR-swizzled source ----
        #pragma unroll
        for (int n = 0; n < 4; ++n) {
            const int r  = n * 32 + (tid >> 3);
            const int sk = ((tid & 7) ^ (r & 7)) * 8;
            gload16(&qkv[(size_t)(b * T_ + it * 128 + r) * QKV_N + C_ + h * HS + sk],
                    &Ks[(n * 256 + tid) * 8]);
        }
        #pragma unroll
        for (int n = 0; n < 4; ++n) {
            const int d  = n * 16 + (tid >> 4);
            const int sv = ((tid & 15) ^ (d & 7)) * 8;
            gload16(&vt[((size_t)(bh * HS + d)) * T_ + it * 128 + sv],
                    &Vs[(n * 256 + tid) * 8]);
        }
        __syncthreads();

        #pragma unroll
        for (int sub = 0; sub < 2; ++sub) {
            const int kbase = it * 128 + sub * 64;
            if (kbase <= qwA + 31)
                process(aqA, accA0, accA1, mA, lA, qwA, qgA, sub, kbase);
            if (kbase <= qwB + 31)
                process(aqB, accB0, accB1, mB, lB, qwB, qgB, sub, kbase);
        }
    }

    // ---- write O = acc^T / l ----
    {
        const float inv = 1.0f / lA;
        unsigned short* orow = &out[(size_t)(b * T_ + qgA) * C_ + h * HS];
        #pragma unroll
        for (int g = 0; g < 4; ++g) {
            uint2 wv;
            wv.x = cvtpk_bf16(accA0[4 * g + 0] * inv, accA0[4 * g + 1] * inv);
            wv.y = cvtpk_bf16(accA0[4 * g + 2] * inv, accA0[4 * g + 3] * inv);
            *reinterpret_cast<uint2*>(&orow[8 * g + 4 * hi]) = wv;
            uint2 wv1;
            wv1.x = cvtpk_bf16(accA1[4 * g + 0] * inv, accA1[4 * g + 1] * inv);
            wv1.y = cvtpk_bf16(accA1[4 * g + 2] * inv, accA1[4 * g + 3] * inv);
            *reinterpret_cast<uint2*>(&orow[32 + 8 * g + 4 * hi]) = wv1;
        }
    }
    {
        const float inv = 1.0f / lB;
        unsigned short* orow = &out[(size_t)(b * T_ + qgB) * C_ + h * HS];
        #pragma unroll
        for (int g = 0; g < 4; ++g) {
            uint2 wv;
            wv.x = cvtpk_bf16(accB0[4 * g + 0] * inv, accB0[4 * g + 1] * inv);
            wv.y = cvtpk_bf16(accB0[4 * g + 2] * inv, accB0[4 * g + 3] * inv);
            *reinterpret_cast<uint2*>(&orow[8 * g + 4 * hi]) = wv;
            uint2 wv1;
            wv1.x = cvtpk_bf16(accB1[4 * g + 0] * inv, accB1[4 * g + 1] * inv);
            wv1.y = cvtpk_bf16(accB1[4 * g + 2] * inv, accB1[4 * g + 3] * inv);
            *reinterpret_cast<uint2*>(&orow[32 + 8 * g + 4 * hi]) = wv1;
        }
    }
}

// ---------------------------------------------------------------------------
extern "C" void kernel_launch(void* const* d_in, const int* in_sizes, int n_in,
                              void* d_out, int out_size, void* d_ws, size_t ws_size,
                              hipStream_t stream)
{
    const float* x    = (const float*)d_in[0];   // [B,T,C]
    const float* Wqkv = (const float*)d_in[1];   // [C,3C]
    const float* bqkv = (const float*)d_in[2];   // [3C]
    const float* Wout = (const float*)d_in[3];   // [C,C]
    const float* bout = (const float*)d_in[4];   // [C]
    float* out = (float*)d_out;                  // [B,T,C] fp32

    char* ws = (char*)d_ws;
    unsigned short* qkvb  = (unsigned short*)ws;                       // 50,331,648
    unsigned short* xb    = (unsigned short*)(ws + 50331648);          // 16,777,216
    unsigned short* attnb = (unsigned short*)(ws + 67108864);          // 16,777,216
    unsigned short* vt_g  = (unsigned short*)(ws + 83886080);          // 16,777,216
    unsigned short* Wqkvt = (unsigned short*)(ws + 100663296);         //  6,291,456
    unsigned short* Woutt = (unsigned short*)(ws + 106954752);         //  2,097,152
    float2* tab           = (float2*)(ws + 109051904);                 //    524,288

    // 1) casts / transposes / tables
    cast_bf16_kernel<<<(size_t)M_ * C_ / (8 * 256), 256, 0, stream>>>(x, xb);
    transpose_cast_kernel<<<dim3(QKV_N / 32, C_ / 32), 256, 0, stream>>>(Wqkv, Wqkvt, C_, QKV_N);
    transpose_cast_kernel<<<dim3(C_ / 32, C_ / 32), 256, 0, stream>>>(Wout, Woutt, C_, C_);
    rope_table_kernel<<<(T_ * HALF) / 256, 256, 0, stream>>>(tab);

    // 2) QKV projection with fused RoPE on q,k columns (bf16 out)
    gemm_mfma_kernel<true, true><<<dim3(QKV_N / 128, M_ / 128), 256, 0, stream>>>(
        xb, Wqkvt, bqkv, tab, qkvb, M_, QKV_N, C_);

    // 3) V^T precompute
    vtrans_kernel<<<B_ * H_ * (T_ / 64), 256, 0, stream>>>(qkvb, vt_g);

    // 4) attention -> attnb [B,T,C] bf16 (paired causal q-tiles)
    attn_mfma3_kernel<<<B_ * H_ * (T_ / 256), 256, 0, stream>>>(qkvb, vt_g, attnb);

    // 5) output projection (fp32 out)
    gemm_mfma_kernel<false, false><<<dim3(C_ / 128, M_ / 128), 256, 0, stream>>>(
        attnb, Woutt, bout, nullptr, out, M_, C_, C_);
}